// Round 1
// baseline (1261.069 us; speedup 1.0000x reference)
//
#include <hip/hip_runtime.h>
#include <cstdint>
#include <cstddef>

typedef unsigned int u32;
typedef unsigned short u16;

#define BB 16
#define CMEL 80
#define DRES 256
#define TXN 1024
#define TYN 4096
#define NEGV (-1e9f)

// output offsets (in floats), concatenated in reference return order
#define OFF_ZM    0ull
#define OFF_ZMASK 16777216ull
#define OFF_ATTN  16842752ull
#define OFF_LOGW  83951616ull
#define OFF_LOSS  83968000ull
#define OFF_MPROJ 83968001ull

// ws offsets (bytes)
#define WS_X2   0
#define WS_Z2   262144
#define WS_IDX  1310720
#define WS_PART 1572864

// ---------------- K1: row norms + z_mask ----------------
__global__ __launch_bounds__(1024) void k1_prep(
    const float* __restrict__ xm, const float* __restrict__ mel,
    const int* __restrict__ mlen,
    float* __restrict__ x2n, float* __restrict__ z2n, float* __restrict__ out_zmask) {
  int b = blockIdx.x;
  int slice = blockIdx.y;
  int t = threadIdx.x;
  if (slice == 0) {
    float acc = 0.f;
    const float* p = xm + (size_t)b * CMEL * TXN + t;
    #pragma unroll 4
    for (int c = 0; c < CMEL; ++c) { float v = p[(size_t)c * TXN]; acc = fmaf(v, v, acc); }
    x2n[b * TXN + t] = -acc;
  } else {
    int j = (slice - 1) * 1024 + t;
    float acc = 0.f;
    const float* p = mel + (size_t)b * CMEL * TYN + j;
    #pragma unroll 4
    for (int c = 0; c < CMEL; ++c) { float v = p[(size_t)c * TYN]; acc = fmaf(v, v, acc); }
    z2n[b * TYN + j] = -acc;
    out_zmask[b * TYN + j] = (j < mlen[b]) ? 1.0f : 0.0f;
  }
}

// ---------------- K2: corr GEMM -> val_T[b][j][x] (masked) ----------------
// tile 128(j) x 128(x), K-chunks of 40, 256 threads, 8x8 micro-tile (strided)
__global__ __launch_bounds__(256) void k2_corr(
    const float* __restrict__ xm, const float* __restrict__ mel,
    const float* __restrict__ x2n, const float* __restrict__ z2n,
    const int* __restrict__ xlen, const int* __restrict__ mlen,
    float* __restrict__ valT) {
  int b = blockIdx.z;
  int ml = mlen[b];
  int j0 = blockIdx.y * 128;
  if (j0 >= ml) return;   // rows never read by DP
  int xl = xlen[b];
  int x0 = blockIdx.x * 128;

  __shared__ float sA[40][128];
  __shared__ float sB[40][128];

  int t = threadIdx.x;
  int i16 = t & 15, j16 = t >> 4;

  float acc[2][4][2][4];  // [p][jj][q][i]
  #pragma unroll
  for (int p = 0; p < 2; ++p)
    #pragma unroll
    for (int jj = 0; jj < 4; ++jj)
      #pragma unroll
      for (int q = 0; q < 2; ++q)
        #pragma unroll
        for (int i = 0; i < 4; ++i) acc[p][jj][q][i] = 0.f;

  for (int c0 = 0; c0 < CMEL; c0 += 40) {
    __syncthreads();
    for (int i = t; i < 40 * 32; i += 256) {
      int c = i >> 5, q = i & 31;
      *(float4*)&sA[c][q * 4] =
          *(const float4*)(xm + (size_t)(b * CMEL + c0 + c) * TXN + x0 + q * 4);
      *(float4*)&sB[c][q * 4] =
          *(const float4*)(mel + (size_t)(b * CMEL + c0 + c) * TYN + j0 + q * 4);
    }
    __syncthreads();
    #pragma unroll 2
    for (int c = 0; c < 40; ++c) {
      float av[2][4], bw[2][4];
      *(float4*)av[0] = *(const float4*)&sA[c][i16 * 4];
      *(float4*)av[1] = *(const float4*)&sA[c][64 + i16 * 4];
      *(float4*)bw[0] = *(const float4*)&sB[c][j16 * 4];
      *(float4*)bw[1] = *(const float4*)&sB[c][64 + j16 * 4];
      #pragma unroll
      for (int p = 0; p < 2; ++p)
        #pragma unroll
        for (int jj = 0; jj < 4; ++jj)
          #pragma unroll
          for (int q = 0; q < 2; ++q)
            #pragma unroll
            for (int i = 0; i < 4; ++i)
              acc[p][jj][q][i] = fmaf(av[q][i], bw[p][jj], acc[p][jj][q][i]);
    }
  }

  float4 xa[2];
  xa[0] = *(const float4*)(x2n + b * TXN + x0 + i16 * 4);
  xa[1] = *(const float4*)(x2n + b * TXN + x0 + 64 + i16 * 4);
  int xb0 = x0 + i16 * 4;
  int xb1 = x0 + 64 + i16 * 4;

  #pragma unroll
  for (int p = 0; p < 2; ++p)
    #pragma unroll
    for (int jj = 0; jj < 4; ++jj) {
      int j = j0 + p * 64 + j16 * 4 + jj;
      if (j >= ml) continue;
      float zz = z2n[b * TYN + j];
      float* row = valT + ((size_t)b * TYN + j) * TXN;
      float4 o;
      o.x = (xb0 + 0 < xl) ? ((xa[0].x + zz) + 2.f * acc[p][jj][0][0]) : 0.f;
      o.y = (xb0 + 1 < xl) ? ((xa[0].y + zz) + 2.f * acc[p][jj][0][1]) : 0.f;
      o.z = (xb0 + 2 < xl) ? ((xa[0].z + zz) + 2.f * acc[p][jj][0][2]) : 0.f;
      o.w = (xb0 + 3 < xl) ? ((xa[0].w + zz) + 2.f * acc[p][jj][0][3]) : 0.f;
      *(float4*)(row + xb0) = o;
      o.x = (xb1 + 0 < xl) ? ((xa[1].x + zz) + 2.f * acc[p][jj][1][0]) : 0.f;
      o.y = (xb1 + 1 < xl) ? ((xa[1].y + zz) + 2.f * acc[p][jj][1][1]) : 0.f;
      o.z = (xb1 + 2 < xl) ? ((xa[1].z + zz) + 2.f * acc[p][jj][1][2]) : 0.f;
      o.w = (xb1 + 3 < xl) ? ((xa[1].w + zz) + 2.f * acc[p][jj][1][3]) : 0.f;
      *(float4*)(row + xb1) = o;
    }
}

// ---------------- K3: Viterbi forward DP ----------------
// one WG per batch, 512 threads x 2 x-values; stay bits packed to staysW[b][x][128 u32]
__global__ __launch_bounds__(512) void k3_dp(
    const float* __restrict__ valT, const int* __restrict__ mlen,
    u32* __restrict__ staysW) {
  int b = blockIdx.x;
  int ml = mlen[b];
  int t = threadIdx.x;
  int lane = t & 63, wid = t >> 6;
  int x0 = 2 * t, x1 = 2 * t + 1;
  __shared__ float edge[2][8];

  const float* base = valT + (size_t)b * TYN * TXN + x0;
  float v0 = 0.f, v1 = 0.f;
  float2 pf[16];
  #pragma unroll
  for (int k = 0; k < 16; ++k) pf[k] = *(const float2*)(base + (size_t)k * TXN);

  u32* sw0 = staysW + ((size_t)(b * TXN + x0) << 7);
  bool isLane0 = (lane == 0);
  bool isEdgeSrc = (lane == 63);
  int ewid = (wid > 0) ? (wid - 1) : 0;

  int jpad = (ml + 31) & ~31;
  for (int j0 = 0; j0 < jpad; j0 += 32) {
    u32 bits0 = 0, bits1 = 0;
    #pragma unroll
    for (int jj = 0; jj < 32; ++jj) {
      int j = j0 + jj;
      if (isEdgeSrc) edge[j & 1][wid] = v1;
      __syncthreads();
      float up = __shfl_up(v1, 1);
      float ev = edge[j & 1][ewid];
      float prev0 = isLane0 ? ((wid > 0) ? ev : NEGV) : up;
      float2 val = pf[jj & 15];
      int jl = j + 16;
      if (jl < ml) pf[jj & 15] = *(const float2*)(base + (size_t)jl * TXN);
      else          pf[jj & 15] = make_float2(0.f, 0.f);
      bool s0 = (v0 >= prev0);
      bool s1 = (v1 >= v0);
      float m0 = s0 ? v0 : prev0;
      float m1 = s1 ? v1 : v0;
      float nv0 = (x0 <= j) ? (m0 + val.x) : NEGV;
      float nv1 = (x1 <= j) ? (m1 + val.y) : NEGV;
      v0 = nv0; v1 = nv1;
      bits0 |= ((u32)s0) << jj;
      bits1 |= ((u32)s1) << jj;
    }
    sw0[j0 >> 5] = bits0;
    sw0[128 + (j0 >> 5)] = bits1;
  }
}

// ---------------- K4: backtrack (run-skipping on transposed bits) ----------------
__global__ __launch_bounds__(256) void k4_backtrack(
    const u32* __restrict__ staysW, const int* __restrict__ xlen, const int* __restrict__ mlen,
    int* __restrict__ idxArr, float* __restrict__ out_logw) {
  int b = blockIdx.x;
  int xl = xlen[b], ml = mlen[b];
  int t = threadIdx.x;
  __shared__ u32 win[64][128];
  __shared__ u16 lidx[TYN];
  __shared__ u16 ldur[TXN];
  __shared__ int st[3];

  for (int i = t; i < TXN; i += 256) ldur[i] = 0;
  if (t == 0) { st[0] = xl - 1; st[1] = ml - 1; st[2] = ml - 1; }
  __syncthreads();

  int wb = (xl - 1) >> 6;
  for (int i = t; i < 64 * 128; i += 256) {
    int r = i >> 7, wq = i & 127;
    win[r][wq] = staysW[((size_t)(b * TXN + (wb << 6) + r) << 7) + wq];
  }
  __syncthreads();

  while (true) {
    if (t == 0) {
      int idx = st[0], j = st[1], end = st[2];
      while (j >= 0 && (idx >> 6) == wb) {
        u32 w = win[idx & 63][j >> 5];
        int p = j & 31;
        u32 below = w << (31 - p);
        u32 inv = ~below;
        int ones = (inv != 0u) ? __builtin_clz(inv) : 32;
        if (ones > p) {
          j -= p + 1;                      // whole rest of word is "stay"
        } else {
          int jz = j - ones;               // dir==0 at step jz -> move down
          for (int q = jz; q <= end; ++q) lidx[q] = (u16)idx;
          ldur[idx] = (u16)(end - jz + 1);
          end = jz - 1;
          j = jz - 1;
          idx -= 1;
        }
      }
      if (j < 0) {
        for (int q = 0; q <= end; ++q) lidx[q] = (u16)idx;
        if (idx >= 0 && end >= 0) ldur[idx] = (u16)(end + 1);
        else if (idx >= 0) ldur[idx] = ldur[idx]; // no-op
      }
      st[0] = idx; st[1] = j; st[2] = end;
    }
    __syncthreads();
    if (st[1] < 0) break;
    wb = st[0] >> 6;
    for (int i = t; i < 64 * 128; i += 256) {
      int r = i >> 7, wq = i & 127;
      win[r][wq] = staysW[((size_t)(b * TXN + (wb << 6) + r) << 7) + wq];
    }
    __syncthreads();
  }

  for (int q = t; q < TYN; q += 256) idxArr[b * TYN + q] = (q < ml) ? (int)lidx[q] : -1;
  for (int x = t; x < TXN; x += 256)
    out_logw[b * TXN + x] = (x < xl) ? logf(1e-8f + (float)ldur[x]) : 0.f;
}

// ---------------- K5a: write attn (full pass, 0/1) ----------------
__global__ __launch_bounds__(256) void k5_attn(
    const int* __restrict__ idxArr, float* __restrict__ attn) {
  int b = blockIdx.z;
  int x = blockIdx.y;
  int j = blockIdx.x * 1024 + threadIdx.x * 4;
  int4 iv = *(const int4*)(idxArr + b * TYN + j);
  float4 o;
  o.x = (iv.x == x) ? 1.f : 0.f;
  o.y = (iv.y == x) ? 1.f : 0.f;
  o.z = (iv.z == x) ? 1.f : 0.f;
  o.w = (iv.w == x) ? 1.f : 0.f;
  *(float4*)(attn + ((size_t)(b * TXN + x)) * TYN + j) = o;
}

// ---------------- K5b: z_m gather ----------------
__global__ __launch_bounds__(256) void k5_zm(
    const int* __restrict__ idxArr, const float* __restrict__ xres, float* __restrict__ zm) {
  int bid = blockIdx.x; int b = bid >> 8; int c = bid & 255;
  const float* row = xres + (size_t)(b * DRES + c) * TXN;
  float* orow = zm + (size_t)(b * DRES + c) * TYN;
  const int* ia = idxArr + b * TYN;
  for (int j = threadIdx.x; j < TYN; j += 256) {
    int idx = ia[j];
    orow[j] = (idx >= 0) ? row[idx] : 0.f;
  }
}

// ---------------- K5c: mel_proj gather + loss partials ----------------
__global__ __launch_bounds__(256) void k5_mproj(
    const int* __restrict__ idxArr, const float* __restrict__ xm,
    const float* __restrict__ noise, const float* __restrict__ mel,
    float* __restrict__ mproj, float* __restrict__ partials) {
  int bid = blockIdx.x; int b = bid / CMEL; int c = bid % CMEL;
  const float* row  = xm    + (size_t)(b * CMEL + c) * TXN;
  const float* nrow = noise + (size_t)(b * CMEL + c) * TYN;
  const float* mrow = mel   + (size_t)(b * CMEL + c) * TYN;
  float* orow = mproj + (size_t)(b * CMEL + c) * TYN;
  const int* ia = idxArr + b * TYN;
  float acc = 0.f;
  for (int j = threadIdx.x; j < TYN; j += 256) {
    int idx = ia[j];
    float g = (idx >= 0) ? row[idx] : 0.f;
    float mp = g + nrow[j];
    orow[j] = mp;
    float d = mp - mrow[j];
    acc += (idx >= 0) ? fabsf(d) : 0.f;
  }
  #pragma unroll
  for (int o = 32; o; o >>= 1) acc += __shfl_down(acc, o);
  __shared__ float ws4[4];
  if ((threadIdx.x & 63) == 0) ws4[threadIdx.x >> 6] = acc;
  __syncthreads();
  if (threadIdx.x == 0) partials[bid] = (ws4[0] + ws4[1]) + (ws4[2] + ws4[3]);
}

// ---------------- K6: final loss reduce ----------------
__global__ __launch_bounds__(256) void k6_loss(
    const float* __restrict__ partials, float* __restrict__ out_loss) {
  float acc = 0.f;
  for (int i = threadIdx.x; i < BB * CMEL; i += 256) acc += partials[i];
  #pragma unroll
  for (int o = 32; o; o >>= 1) acc += __shfl_down(acc, o);
  __shared__ float ws4[4];
  if ((threadIdx.x & 63) == 0) ws4[threadIdx.x >> 6] = acc;
  __syncthreads();
  if (threadIdx.x == 0)
    out_loss[0] = ((ws4[0] + ws4[1]) + (ws4[2] + ws4[3])) * (1.0f / ((float)BB * CMEL * TYN));
}

extern "C" void kernel_launch(void* const* d_in, const int* in_sizes, int n_in,
                              void* d_out, int out_size, void* d_ws, size_t ws_size,
                              hipStream_t stream) {
  const float* xm    = (const float*)d_in[0];
  const float* xres  = (const float*)d_in[1];
  const float* mel   = (const float*)d_in[2];
  const int*   xlen  = (const int*)d_in[3];
  const int*   mlen  = (const int*)d_in[4];
  const float* noise = (const float*)d_in[5];

  float* out = (float*)d_out;
  float* out_zm    = out + OFF_ZM;
  float* out_zmask = out + OFF_ZMASK;
  float* out_attn  = out + OFF_ATTN;
  float* out_logw  = out + OFF_LOGW;
  float* out_loss  = out + OFF_LOSS;
  float* out_mproj = out + OFF_MPROJ;

  char* ws = (char*)d_ws;
  float* x2n      = (float*)(ws + WS_X2);
  float* z2n      = (float*)(ws + WS_Z2);
  int*   idxArr   = (int*)(ws + WS_IDX);
  float* partials = (float*)(ws + WS_PART);

  // scratch aliases inside output regions (consumed before region is rewritten)
  float* valT   = out_attn;        // [b][j][x], read by K3, overwritten by K5a
  u32*   staysW = (u32*)out_zm;    // 8 MB of z_m region, read by K4, overwritten by K5b

  hipLaunchKernelGGL(k1_prep, dim3(BB, 5), dim3(1024), 0, stream, xm, mel, mlen, x2n, z2n, out_zmask);
  hipLaunchKernelGGL(k2_corr, dim3(8, 32, BB), dim3(256), 0, stream, xm, mel, x2n, z2n, xlen, mlen, valT);
  hipLaunchKernelGGL(k3_dp, dim3(BB), dim3(512), 0, stream, valT, mlen, staysW);
  hipLaunchKernelGGL(k4_backtrack, dim3(BB), dim3(256), 0, stream, staysW, xlen, mlen, idxArr, out_logw);
  hipLaunchKernelGGL(k5_attn, dim3(4, TXN, BB), dim3(256), 0, stream, idxArr, out_attn);
  hipLaunchKernelGGL(k5_zm, dim3(BB * DRES), dim3(256), 0, stream, idxArr, xres, out_zm);
  hipLaunchKernelGGL(k5_mproj, dim3(BB * CMEL), dim3(256), 0, stream, idxArr, xm, noise, mel, out_mproj, partials);
  hipLaunchKernelGGL(k6_loss, dim3(1), dim3(256), 0, stream, partials, out_loss);
}

// Round 2
// 1202.453 us; speedup vs baseline: 1.0487x; 1.0487x over previous
//
#include <hip/hip_runtime.h>
#include <cstdint>
#include <cstddef>

typedef unsigned int u32;
typedef unsigned short u16;

#define BB 16
#define CMEL 80
#define DRES 256
#define TXN 1024
#define TYN 4096
#define NEGV (-1e9f)

// output offsets (in floats), concatenated in reference return order
#define OFF_ZM    0ull
#define OFF_ZMASK 16777216ull
#define OFF_ATTN  16842752ull
#define OFF_LOGW  83951616ull
#define OFF_LOSS  83968000ull
#define OFF_MPROJ 83968001ull

// ws offsets (bytes)
#define WS_X2   0
#define WS_Z2   262144
#define WS_IDX  1310720
#define WS_PART 1572864

// ---------------- K1: row norms + z_mask ----------------
__global__ __launch_bounds__(1024) void k1_prep(
    const float* __restrict__ xm, const float* __restrict__ mel,
    const int* __restrict__ mlen,
    float* __restrict__ x2n, float* __restrict__ z2n, float* __restrict__ out_zmask) {
  int b = blockIdx.x;
  int slice = blockIdx.y;
  int t = threadIdx.x;
  if (slice == 0) {
    float acc = 0.f;
    const float* p = xm + (size_t)b * CMEL * TXN + t;
    #pragma unroll 4
    for (int c = 0; c < CMEL; ++c) { float v = p[(size_t)c * TXN]; acc = fmaf(v, v, acc); }
    x2n[b * TXN + t] = -acc;
  } else {
    int j = (slice - 1) * 1024 + t;
    float acc = 0.f;
    const float* p = mel + (size_t)b * CMEL * TYN + j;
    #pragma unroll 4
    for (int c = 0; c < CMEL; ++c) { float v = p[(size_t)c * TYN]; acc = fmaf(v, v, acc); }
    z2n[b * TYN + j] = -acc;
    out_zmask[b * TYN + j] = (j < mlen[b]) ? 1.0f : 0.0f;
  }
}

// ---------------- K2: corr GEMM -> val_T[b][j][x] (masked) ----------------
// tile 128(j) x 128(x), K-chunks of 40, 256 threads, 8x8 micro-tile (strided)
// NOTE: accumulation structure frozen — it bit-matches the numpy reference
// (R1 absmax 0.0); changing summation order risks flipping DP decisions.
__global__ __launch_bounds__(256) void k2_corr(
    const float* __restrict__ xm, const float* __restrict__ mel,
    const float* __restrict__ x2n, const float* __restrict__ z2n,
    const int* __restrict__ xlen, const int* __restrict__ mlen,
    float* __restrict__ valT) {
  int b = blockIdx.z;
  int ml = mlen[b];
  int j0 = blockIdx.y * 128;
  if (j0 >= ml) return;   // rows never read by DP
  int xl = xlen[b];
  int x0 = blockIdx.x * 128;

  __shared__ float sA[40][128];
  __shared__ float sB[40][128];

  int t = threadIdx.x;
  int i16 = t & 15, j16 = t >> 4;

  float acc[2][4][2][4];  // [p][jj][q][i]
  #pragma unroll
  for (int p = 0; p < 2; ++p)
    #pragma unroll
    for (int jj = 0; jj < 4; ++jj)
      #pragma unroll
      for (int q = 0; q < 2; ++q)
        #pragma unroll
        for (int i = 0; i < 4; ++i) acc[p][jj][q][i] = 0.f;

  for (int c0 = 0; c0 < CMEL; c0 += 40) {
    __syncthreads();
    for (int i = t; i < 40 * 32; i += 256) {
      int c = i >> 5, q = i & 31;
      *(float4*)&sA[c][q * 4] =
          *(const float4*)(xm + (size_t)(b * CMEL + c0 + c) * TXN + x0 + q * 4);
      *(float4*)&sB[c][q * 4] =
          *(const float4*)(mel + (size_t)(b * CMEL + c0 + c) * TYN + j0 + q * 4);
    }
    __syncthreads();
    #pragma unroll 2
    for (int c = 0; c < 40; ++c) {
      float av[2][4], bw[2][4];
      *(float4*)av[0] = *(const float4*)&sA[c][i16 * 4];
      *(float4*)av[1] = *(const float4*)&sA[c][64 + i16 * 4];
      *(float4*)bw[0] = *(const float4*)&sB[c][j16 * 4];
      *(float4*)bw[1] = *(const float4*)&sB[c][64 + j16 * 4];
      #pragma unroll
      for (int p = 0; p < 2; ++p)
        #pragma unroll
        for (int jj = 0; jj < 4; ++jj)
          #pragma unroll
          for (int q = 0; q < 2; ++q)
            #pragma unroll
            for (int i = 0; i < 4; ++i)
              acc[p][jj][q][i] = fmaf(av[q][i], bw[p][jj], acc[p][jj][q][i]);
    }
  }

  float4 xa[2];
  xa[0] = *(const float4*)(x2n + b * TXN + x0 + i16 * 4);
  xa[1] = *(const float4*)(x2n + b * TXN + x0 + 64 + i16 * 4);
  int xb0 = x0 + i16 * 4;
  int xb1 = x0 + 64 + i16 * 4;

  #pragma unroll
  for (int p = 0; p < 2; ++p)
    #pragma unroll
    for (int jj = 0; jj < 4; ++jj) {
      int j = j0 + p * 64 + j16 * 4 + jj;
      if (j >= ml) continue;
      float zz = z2n[b * TYN + j];
      float* row = valT + ((size_t)b * TYN + j) * TXN;
      float4 o;
      o.x = (xb0 + 0 < xl) ? ((xa[0].x + zz) + 2.f * acc[p][jj][0][0]) : 0.f;
      o.y = (xb0 + 1 < xl) ? ((xa[0].y + zz) + 2.f * acc[p][jj][0][1]) : 0.f;
      o.z = (xb0 + 2 < xl) ? ((xa[0].z + zz) + 2.f * acc[p][jj][0][2]) : 0.f;
      o.w = (xb0 + 3 < xl) ? ((xa[0].w + zz) + 2.f * acc[p][jj][0][3]) : 0.f;
      *(float4*)(row + xb0) = o;
      o.x = (xb1 + 0 < xl) ? ((xa[1].x + zz) + 2.f * acc[p][jj][1][0]) : 0.f;
      o.y = (xb1 + 1 < xl) ? ((xa[1].y + zz) + 2.f * acc[p][jj][1][1]) : 0.f;
      o.z = (xb1 + 2 < xl) ? ((xa[1].z + zz) + 2.f * acc[p][jj][1][2]) : 0.f;
      o.w = (xb1 + 3 < xl) ? ((xa[1].w + zz) + 2.f * acc[p][jj][1][3]) : 0.f;
      *(float4*)(row + xb1) = o;
    }
}

// ---------------- K3: Viterbi forward DP (single wave per batch) ----------------
// 64 lanes x 16 consecutive x/lane. No barriers, no LDS. One shfl_up per step.
// Reference's per-step where(x<=j,...,NEG) replaced by forcing v[j+1]=NEG at the
// end of step j (exact-equivalent for all cells the backtrack can read).
// stays bit layout: staysW[b][x][128 u32 words], bit jj of word w = stay at j=32w+jj.
__global__ __launch_bounds__(64) void k3_dp(
    const float* __restrict__ valT, const int* __restrict__ mlen,
    u32* __restrict__ staysW) {
  int b = blockIdx.x;
  int ml = mlen[b];
  int lane = threadIdx.x;
  int xbase = lane << 4;

  float v[16];
  #pragma unroll
  for (int i = 0; i < 16; ++i) v[i] = NEGV;
  if (lane == 0) v[0] = 0.f;

  // 8-row register prefetch ring: pf[row&7][q] = 16 floats/lane
  float4 pf[8][4];
  #pragma unroll
  for (int k = 0; k < 8; ++k) {
    const float* rowp = valT + (((size_t)(b * TYN + k)) << 10);
    #pragma unroll
    for (int q = 0; q < 4; ++q)
      pf[k][q] = *(const float4*)(rowp + (xbase + (q << 2)));
  }

  u32* swb = staysW + (((size_t)(b * TXN + xbase)) << 7);
  int jpad = (ml + 31) & ~31;

  for (int j0 = 0; j0 < jpad; j0 += 32) {
    u32 bits[16];
    #pragma unroll
    for (int i = 0; i < 16; ++i) bits[i] = 0;

    #pragma unroll
    for (int jj = 0; jj < 32; ++jj) {
      const int j = j0 + jj;
      // cross-lane edge: neighbor's old v[15]; global x=-1 edge is NEG
      float e = __shfl_up(v[15], 1);
      if (lane == 0) e = NEGV;

      float val[16];
      #pragma unroll
      for (int q = 0; q < 4; ++q) {
        val[4 * q + 0] = pf[jj & 7][q].x;
        val[4 * q + 1] = pf[jj & 7][q].y;
        val[4 * q + 2] = pf[jj & 7][q].z;
        val[4 * q + 3] = pf[jj & 7][q].w;
      }

      // descending i so v[i-1] is the previous step's value
      #pragma unroll
      for (int i = 15; i >= 1; --i) {
        bool s = v[i] >= v[i - 1];
        float m = s ? v[i] : v[i - 1];
        v[i] = m + val[i];
        bits[i] |= ((u32)s) << jj;
      }
      {
        bool s = v[0] >= e;
        float m = s ? v[0] : e;
        v[0] = m + val[0];
        bits[0] |= ((u32)s) << jj;
      }

      // force one-above-diagonal cell to exact NEG (register index is
      // compile-time: (j+1)&15 == (jj+1)&15 since j0 % 32 == 0)
      {
        int lt = (j + 1) >> 4;
        if (lane == lt) v[(jj + 1) & 15] = NEGV;
      }

      // prefetch row j+8 into the slot just consumed
      {
        int jn = j + 8; if (jn > TYN - 1) jn = TYN - 1;
        const float* rowp = valT + (((size_t)(b * TYN + jn)) << 10);
        #pragma unroll
        for (int q = 0; q < 4; ++q)
          pf[jj & 7][q] = *(const float4*)(rowp + (xbase + (q << 2)));
      }
    }

    const int w = j0 >> 5;
    #pragma unroll
    for (int i = 0; i < 16; ++i) swb[(i << 7) + w] = bits[i];
  }
}

// ---------------- K4: backtrack (run-skipping on transposed bits) ----------------
__global__ __launch_bounds__(256) void k4_backtrack(
    const u32* __restrict__ staysW, const int* __restrict__ xlen, const int* __restrict__ mlen,
    int* __restrict__ idxArr, float* __restrict__ out_logw) {
  int b = blockIdx.x;
  int xl = xlen[b], ml = mlen[b];
  int t = threadIdx.x;
  __shared__ u32 win[64][128];
  __shared__ u16 lidx[TYN];
  __shared__ u16 ldur[TXN];
  __shared__ int st[3];

  for (int i = t; i < TXN; i += 256) ldur[i] = 0;
  if (t == 0) { st[0] = xl - 1; st[1] = ml - 1; st[2] = ml - 1; }
  __syncthreads();

  int wb = (xl - 1) >> 6;
  for (int i = t; i < 64 * 128; i += 256) {
    int r = i >> 7, wq = i & 127;
    win[r][wq] = staysW[((size_t)(b * TXN + (wb << 6) + r) << 7) + wq];
  }
  __syncthreads();

  while (true) {
    if (t == 0) {
      int idx = st[0], j = st[1], end = st[2];
      while (j >= 0 && (idx >> 6) == wb) {
        u32 w = win[idx & 63][j >> 5];
        int p = j & 31;
        u32 below = w << (31 - p);
        u32 inv = ~below;
        int ones = (inv != 0u) ? __builtin_clz(inv) : 32;
        if (ones > p) {
          j -= p + 1;                      // whole rest of word is "stay"
        } else {
          int jz = j - ones;               // dir==0 at step jz -> move down
          for (int q = jz; q <= end; ++q) lidx[q] = (u16)idx;
          ldur[idx] = (u16)(end - jz + 1);
          end = jz - 1;
          j = jz - 1;
          idx -= 1;
        }
      }
      if (j < 0) {
        for (int q = 0; q <= end; ++q) lidx[q] = (u16)idx;
        if (idx >= 0 && end >= 0) ldur[idx] = (u16)(end + 1);
      }
      st[0] = idx; st[1] = j; st[2] = end;
    }
    __syncthreads();
    if (st[1] < 0) break;
    wb = st[0] >> 6;
    for (int i = t; i < 64 * 128; i += 256) {
      int r = i >> 7, wq = i & 127;
      win[r][wq] = staysW[((size_t)(b * TXN + (wb << 6) + r) << 7) + wq];
    }
    __syncthreads();
  }

  for (int q = t; q < TYN; q += 256) idxArr[b * TYN + q] = (q < ml) ? (int)lidx[q] : -1;
  for (int x = t; x < TXN; x += 256)
    out_logw[b * TXN + x] = (x < xl) ? logf(1e-8f + (float)ldur[x]) : 0.f;
}

// ---------------- K5a: write attn (full pass, 0/1) ----------------
__global__ __launch_bounds__(256) void k5_attn(
    const int* __restrict__ idxArr, float* __restrict__ attn) {
  int b = blockIdx.z;
  int x = blockIdx.y;
  int j = blockIdx.x * 1024 + threadIdx.x * 4;
  int4 iv = *(const int4*)(idxArr + b * TYN + j);
  float4 o;
  o.x = (iv.x == x) ? 1.f : 0.f;
  o.y = (iv.y == x) ? 1.f : 0.f;
  o.z = (iv.z == x) ? 1.f : 0.f;
  o.w = (iv.w == x) ? 1.f : 0.f;
  *(float4*)(attn + ((size_t)(b * TXN + x)) * TYN + j) = o;
}

// ---------------- K5b: z_m gather ----------------
__global__ __launch_bounds__(256) void k5_zm(
    const int* __restrict__ idxArr, const float* __restrict__ xres, float* __restrict__ zm) {
  int bid = blockIdx.x; int b = bid >> 8; int c = bid & 255;
  const float* row = xres + (size_t)(b * DRES + c) * TXN;
  float* orow = zm + (size_t)(b * DRES + c) * TYN;
  const int* ia = idxArr + b * TYN;
  for (int j = threadIdx.x; j < TYN; j += 256) {
    int idx = ia[j];
    orow[j] = (idx >= 0) ? row[idx] : 0.f;
  }
}

// ---------------- K5c: mel_proj gather + loss partials ----------------
__global__ __launch_bounds__(256) void k5_mproj(
    const int* __restrict__ idxArr, const float* __restrict__ xm,
    const float* __restrict__ noise, const float* __restrict__ mel,
    float* __restrict__ mproj, float* __restrict__ partials) {
  int bid = blockIdx.x; int b = bid / CMEL; int c = bid % CMEL;
  const float* row  = xm    + (size_t)(b * CMEL + c) * TXN;
  const float* nrow = noise + (size_t)(b * CMEL + c) * TYN;
  const float* mrow = mel   + (size_t)(b * CMEL + c) * TYN;
  float* orow = mproj + (size_t)(b * CMEL + c) * TYN;
  const int* ia = idxArr + b * TYN;
  float acc = 0.f;
  for (int j = threadIdx.x; j < TYN; j += 256) {
    int idx = ia[j];
    float g = (idx >= 0) ? row[idx] : 0.f;
    float mp = g + nrow[j];
    orow[j] = mp;
    float d = mp - mrow[j];
    acc += (idx >= 0) ? fabsf(d) : 0.f;
  }
  #pragma unroll
  for (int o = 32; o; o >>= 1) acc += __shfl_down(acc, o);
  __shared__ float ws4[4];
  if ((threadIdx.x & 63) == 0) ws4[threadIdx.x >> 6] = acc;
  __syncthreads();
  if (threadIdx.x == 0) partials[bid] = (ws4[0] + ws4[1]) + (ws4[2] + ws4[3]);
}

// ---------------- K6: final loss reduce ----------------
__global__ __launch_bounds__(256) void k6_loss(
    const float* __restrict__ partials, float* __restrict__ out_loss) {
  float acc = 0.f;
  for (int i = threadIdx.x; i < BB * CMEL; i += 256) acc += partials[i];
  #pragma unroll
  for (int o = 32; o; o >>= 1) acc += __shfl_down(acc, o);
  __shared__ float ws4[4];
  if ((threadIdx.x & 63) == 0) ws4[threadIdx.x >> 6] = acc;
  __syncthreads();
  if (threadIdx.x == 0)
    out_loss[0] = ((ws4[0] + ws4[1]) + (ws4[2] + ws4[3])) * (1.0f / ((float)BB * CMEL * TYN));
}

extern "C" void kernel_launch(void* const* d_in, const int* in_sizes, int n_in,
                              void* d_out, int out_size, void* d_ws, size_t ws_size,
                              hipStream_t stream) {
  const float* xm    = (const float*)d_in[0];
  const float* xres  = (const float*)d_in[1];
  const float* mel   = (const float*)d_in[2];
  const int*   xlen  = (const int*)d_in[3];
  const int*   mlen  = (const int*)d_in[4];
  const float* noise = (const float*)d_in[5];

  float* out = (float*)d_out;
  float* out_zm    = out + OFF_ZM;
  float* out_zmask = out + OFF_ZMASK;
  float* out_attn  = out + OFF_ATTN;
  float* out_logw  = out + OFF_LOGW;
  float* out_loss  = out + OFF_LOSS;
  float* out_mproj = out + OFF_MPROJ;

  char* ws = (char*)d_ws;
  float* x2n      = (float*)(ws + WS_X2);
  float* z2n      = (float*)(ws + WS_Z2);
  int*   idxArr   = (int*)(ws + WS_IDX);
  float* partials = (float*)(ws + WS_PART);

  // scratch aliases inside output regions (consumed before region is rewritten)
  float* valT   = out_attn;        // [b][j][x], read by K3, overwritten by K5a
  u32*   staysW = (u32*)out_zm;    // 8 MB of z_m region, read by K4, overwritten by K5b

  hipLaunchKernelGGL(k1_prep, dim3(BB, 5), dim3(1024), 0, stream, xm, mel, mlen, x2n, z2n, out_zmask);
  hipLaunchKernelGGL(k2_corr, dim3(8, 32, BB), dim3(256), 0, stream, xm, mel, x2n, z2n, xlen, mlen, valT);
  hipLaunchKernelGGL(k3_dp, dim3(BB), dim3(64), 0, stream, valT, mlen, staysW);
  hipLaunchKernelGGL(k4_backtrack, dim3(BB), dim3(256), 0, stream, staysW, xlen, mlen, idxArr, out_logw);
  hipLaunchKernelGGL(k5_attn, dim3(4, TXN, BB), dim3(256), 0, stream, idxArr, out_attn);
  hipLaunchKernelGGL(k5_zm, dim3(BB * DRES), dim3(256), 0, stream, idxArr, xres, out_zm);
  hipLaunchKernelGGL(k5_mproj, dim3(BB * CMEL), dim3(256), 0, stream, idxArr, xm, noise, mel, out_mproj, partials);
  hipLaunchKernelGGL(k6_loss, dim3(1), dim3(256), 0, stream, partials, out_loss);
}